// Round 1
// baseline (608.803 us; speedup 1.0000x reference)
//
#include <hip/hip_runtime.h>

#define D 256
#define NPATHS 4096
#define PLEN 64
#define NSTEPS (NPATHS * PLEN)   /* 262144 */
#define NNODES 10000

// ---------------- K1: q = prev @ Wq  [NNODES, D] ----------------
__global__ __launch_bounds__(256) void k_query(const float* __restrict__ prev,
                                               const float* __restrict__ Wq,
                                               float* __restrict__ q) {
    __shared__ float a[32][D];
    const int tid = threadIdx.x;
    const int row0 = blockIdx.x * 32;
    for (int i = tid; i < 32 * D; i += 256) {
        int r = i >> 8, c = i & 255;
        int row = row0 + r;
        a[r][c] = (row < NNODES) ? prev[row * D + c] : 0.f;
    }
    __syncthreads();
    float acc[32];
#pragma unroll
    for (int r = 0; r < 32; ++r) acc[r] = 0.f;
    for (int k = 0; k < D; k += 4) {
        float w0 = Wq[(k + 0) * D + tid];
        float w1 = Wq[(k + 1) * D + tid];
        float w2 = Wq[(k + 2) * D + tid];
        float w3 = Wq[(k + 3) * D + tid];
#pragma unroll
        for (int r = 0; r < 32; ++r) {
            float4 av = *reinterpret_cast<const float4*>(&a[r][k]);
            acc[r] += av.x * w0 + av.y * w1 + av.z * w2 + av.w * w3;
        }
    }
    for (int r = 0; r < 32; ++r) {
        int row = row0 + r;
        if (row < NNODES) q[row * D + tid] = acc[r];
    }
}

// ---------------- K2: per-step score dot + per-node histogram ----------------
// one wave (64 lanes) per path-step; masked steps skipped entirely
__global__ __launch_bounds__(256) void k_scores(const float* __restrict__ x,
                                                const int* __restrict__ mask,
                                                const int* __restrict__ nidx,
                                                const float* __restrict__ q,
                                                float* __restrict__ scores,
                                                int* __restrict__ counts) {
    const int wave = threadIdx.x >> 6;
    const int lane = threadIdx.x & 63;
    const int step = blockIdx.x * 4 + wave;
    if (step >= NSTEPS) return;
    if (!mask[step]) return;  // masked: never read downstream
    const int node = nidx[step];
    const float4* x4 = reinterpret_cast<const float4*>(x) + step * 64;
    const float4* q4 = reinterpret_cast<const float4*>(q) + node * 64;
    float4 xa = x4[lane];
    float4 qa = q4[lane];
    float v = xa.x * qa.x + xa.y * qa.y + xa.z * qa.z + xa.w * qa.w;
    v += __shfl_down(v, 32);
    v += __shfl_down(v, 16);
    v += __shfl_down(v, 8);
    v += __shfl_down(v, 4);
    v += __shfl_down(v, 2);
    v += __shfl_down(v, 1);
    if (lane == 0) {
        scores[step] = v * 0.0625f;  // 1/sqrt(256)
        atomicAdd(&counts[node], 1);
    }
}

// ---------------- K3: exclusive scan of counts -> offsets (+cursor copy) ----
__global__ __launch_bounds__(256) void k_scan(const int* __restrict__ counts,
                                              int* __restrict__ offsets,
                                              int* __restrict__ cursor) {
    __shared__ int sums[256];
    __shared__ int scan[257];
    const int tid = threadIdx.x;
    const int CH = 40;  // 256*40 = 10240 >= NNODES
    const int base = tid * CH;
    int s = 0;
    for (int i = 0; i < CH; ++i) {
        int j = base + i;
        if (j < NNODES) s += counts[j];
    }
    sums[tid] = s;
    __syncthreads();
    if (tid == 0) {
        int run = 0;
        for (int t = 0; t < 256; ++t) { scan[t] = run; run += sums[t]; }
        scan[256] = run;
    }
    __syncthreads();
    int run = scan[tid];
    for (int i = 0; i < CH; ++i) {
        int j = base + i;
        if (j < NNODES) {
            offsets[j] = run;
            cursor[j] = run;
            run += counts[j];
        }
    }
    if (tid == 0) offsets[NNODES] = scan[256];
}

// ---------------- K4: fill perm with unmasked step ids grouped by node ------
__global__ __launch_bounds__(256) void k_perm(const int* __restrict__ mask,
                                              const int* __restrict__ nidx,
                                              int* __restrict__ cursor,
                                              int* __restrict__ perm) {
    const int step = blockIdx.x * 256 + threadIdx.x;
    if (step >= NSTEPS) return;
    if (!mask[step]) return;
    const int node = nidx[step];
    int p = atomicAdd(&cursor[node], 1);
    perm[p] = step;
}

// ---------------- K5: per-node softmax + weighted accumulate ----------------
__global__ __launch_bounds__(256) void k_combine(const float* __restrict__ x,
                                                 const float* __restrict__ scores,
                                                 const int* __restrict__ offsets,
                                                 const int* __restrict__ perm,
                                                 float* __restrict__ update) {
    const int node = blockIdx.x;
    const int tid = threadIdx.x;
    const int off = offsets[node];
    const int cnt = offsets[node + 1] - off;
    if (cnt == 0) {
        update[node * D + tid] = 0.f;
        return;
    }
    __shared__ float red[256];
    __shared__ float smax_s, denom_s;
    // max
    float lm = -3.0e38f;
    for (int i = tid; i < cnt; i += 256) lm = fmaxf(lm, scores[perm[off + i]]);
    red[tid] = lm;
    __syncthreads();
    for (int s = 128; s > 0; s >>= 1) {
        if (tid < s) red[tid] = fmaxf(red[tid], red[tid + s]);
        __syncthreads();
    }
    if (tid == 0) smax_s = red[0];
    __syncthreads();
    const float smax = smax_s;
    // denom
    float ls = 0.f;
    for (int i = tid; i < cnt; i += 256) ls += expf(scores[perm[off + i]] - smax);
    __syncthreads();
    red[tid] = ls;
    __syncthreads();
    for (int s = 128; s > 0; s >>= 1) {
        if (tid < s) red[tid] += red[tid + s];
        __syncthreads();
    }
    if (tid == 0) denom_s = red[0];
    __syncthreads();
    const float invD = 1.f / fmaxf(denom_s, 1e-9f);
    // weighted accumulate: thread tid owns column tid
    __shared__ int ids[64];
    __shared__ float wts[64];
    float acc = 0.f;
    for (int base = 0; base < cnt; base += 64) {
        if (tid < 64 && base + tid < cnt) {
            int n = perm[off + base + tid];
            ids[tid] = n;
            wts[tid] = expf(scores[n] - smax) * invD;
        }
        __syncthreads();
        int lim = min(64, cnt - base);
        for (int i = 0; i < lim; ++i) {
            acc += wts[i] * x[(size_t)ids[i] * D + tid];
        }
        __syncthreads();
    }
    update[node * D + tid] = acc;
}

// ---------------- K6: gated blend ----------------
__global__ __launch_bounds__(256) void k_gate(const float* __restrict__ prev,
                                              const float* __restrict__ update,
                                              const float* __restrict__ gW,
                                              const float* __restrict__ gb,
                                              float* __restrict__ out) {
    __shared__ float pa[16][D];
    __shared__ float ua[16][D];
    const int tid = threadIdx.x;
    const int row0 = blockIdx.x * 16;
    for (int i = tid; i < 16 * D; i += 256) {
        int r = i >> 8, c = i & 255;
        int row = row0 + r;
        pa[r][c] = (row < NNODES) ? prev[row * D + c] : 0.f;
        ua[r][c] = (row < NNODES) ? update[row * D + c] : 0.f;
    }
    __syncthreads();
    float acc[16];
#pragma unroll
    for (int r = 0; r < 16; ++r) acc[r] = 0.f;
    for (int k = 0; k < D; k += 4) {
        float w0 = gW[(k + 0) * D + tid];
        float w1 = gW[(k + 1) * D + tid];
        float w2 = gW[(k + 2) * D + tid];
        float w3 = gW[(k + 3) * D + tid];
#pragma unroll
        for (int r = 0; r < 16; ++r) {
            float4 av = *reinterpret_cast<const float4*>(&pa[r][k]);
            acc[r] += av.x * w0 + av.y * w1 + av.z * w2 + av.w * w3;
        }
    }
    for (int k = 0; k < D; k += 4) {
        float w0 = gW[(256 + k + 0) * D + tid];
        float w1 = gW[(256 + k + 1) * D + tid];
        float w2 = gW[(256 + k + 2) * D + tid];
        float w3 = gW[(256 + k + 3) * D + tid];
#pragma unroll
        for (int r = 0; r < 16; ++r) {
            float4 av = *reinterpret_cast<const float4*>(&ua[r][k]);
            acc[r] += av.x * w0 + av.y * w1 + av.z * w2 + av.w * w3;
        }
    }
    const float b = gb[tid];
    for (int r = 0; r < 16; ++r) {
        int row = row0 + r;
        if (row < NNODES) {
            float g = 1.f / (1.f + expf(-(acc[r] + b)));
            out[row * D + tid] = g * pa[r][tid] + (1.f - g) * ua[r][tid];
        }
    }
}

extern "C" void kernel_launch(void* const* d_in, const int* in_sizes, int n_in,
                              void* d_out, int out_size, void* d_ws, size_t ws_size,
                              hipStream_t stream) {
    const float* enc   = (const float*)d_in[0];  // [4096,64,256]
    const int*   mask  = (const int*)d_in[1];    // [4096,64] bool->int32
    const int*   nidx  = (const int*)d_in[2];    // [4096,64]
    const float* prev  = (const float*)d_in[3];  // [10000,256]
    const float* Wq    = (const float*)d_in[4];  // [256,256]
    const float* gW    = (const float*)d_in[5];  // [512,256]
    const float* gb    = (const float*)d_in[6];  // [256]
    float* out = (float*)d_out;

    // workspace layout (all offsets 256B-aligned)
    char* ws = (char*)d_ws;
    float* q       = (float*)(ws + 0);           // 10,240,000 B
    float* scores  = (float*)(ws + 10240000);    //  1,048,576 B
    int*   counts  = (int*)  (ws + 11288576);    //     40,000 B
    int*   offsets = (int*)  (ws + 11328768);    //     40,004 B
    int*   cursor  = (int*)  (ws + 11369216);    //     40,000 B
    int*   perm    = (int*)  (ws + 11409408);    //  1,048,576 B
    float* update  = (float*)(ws + 12457984);    // 10,240,000 B
    // total ~22.7 MB

    hipMemsetAsync(counts, 0, NNODES * sizeof(int), stream);

    k_query<<<(NNODES + 31) / 32, 256, 0, stream>>>(prev, Wq, q);
    k_scores<<<NSTEPS / 4, 256, 0, stream>>>(enc, mask, nidx, q, scores, counts);
    k_scan<<<1, 256, 0, stream>>>(counts, offsets, cursor);
    k_perm<<<NSTEPS / 256, 256, 0, stream>>>(mask, nidx, cursor, perm);
    k_combine<<<NNODES, 256, 0, stream>>>(enc, scores, offsets, perm, update);
    k_gate<<<(NNODES + 15) / 16, 256, 0, stream>>>(prev, update, gW, gb, out);
}

// Round 2
// 584.913 us; speedup vs baseline: 1.0408x; 1.0408x over previous
//
#include <hip/hip_runtime.h>

#define D 256
#define NPATHS 4096
#define PLEN 64
#define NSTEPS (NPATHS * PLEN)   /* 262144 */
#define NNODES 10000

// ---------------- K1: q = prev @ Wq  [NNODES, D] ----------------
__global__ __launch_bounds__(256) void k_query(const float* __restrict__ prev,
                                               const float* __restrict__ Wq,
                                               float* __restrict__ q) {
    __shared__ float a[32][D];
    const int tid = threadIdx.x;
    const int row0 = blockIdx.x * 32;
    for (int i = tid; i < 32 * D; i += 256) {
        int r = i >> 8, c = i & 255;
        int row = row0 + r;
        a[r][c] = (row < NNODES) ? prev[row * D + c] : 0.f;
    }
    __syncthreads();
    float acc[32];
#pragma unroll
    for (int r = 0; r < 32; ++r) acc[r] = 0.f;
    for (int k = 0; k < D; k += 4) {
        float w0 = Wq[(k + 0) * D + tid];
        float w1 = Wq[(k + 1) * D + tid];
        float w2 = Wq[(k + 2) * D + tid];
        float w3 = Wq[(k + 3) * D + tid];
#pragma unroll
        for (int r = 0; r < 32; ++r) {
            float4 av = *reinterpret_cast<const float4*>(&a[r][k]);
            acc[r] += av.x * w0 + av.y * w1 + av.z * w2 + av.w * w3;
        }
    }
    for (int r = 0; r < 32; ++r) {
        int row = row0 + r;
        if (row < NNODES) q[row * D + tid] = acc[r];
    }
}

// ---------------- K2: per-node histogram of unmasked steps ----------------
__global__ __launch_bounds__(256) void k_count(const int* __restrict__ mask,
                                               const int* __restrict__ nidx,
                                               int* __restrict__ counts) {
    const int step = blockIdx.x * 256 + threadIdx.x;
    if (step >= NSTEPS) return;
    if (!mask[step]) return;
    atomicAdd(&counts[nidx[step]], 1);
}

// ---------------- K3: exclusive scan of counts -> offsets (+cursor copy) ----
__global__ __launch_bounds__(256) void k_scan(const int* __restrict__ counts,
                                              int* __restrict__ offsets,
                                              int* __restrict__ cursor) {
    __shared__ int sums[256];
    __shared__ int scan[257];
    const int tid = threadIdx.x;
    const int CH = 40;  // 256*40 = 10240 >= NNODES
    const int base = tid * CH;
    int s = 0;
    for (int i = 0; i < CH; ++i) {
        int j = base + i;
        if (j < NNODES) s += counts[j];
    }
    sums[tid] = s;
    __syncthreads();
    if (tid == 0) {
        int run = 0;
        for (int t = 0; t < 256; ++t) { scan[t] = run; run += sums[t]; }
        scan[256] = run;
    }
    __syncthreads();
    int run = scan[tid];
    for (int i = 0; i < CH; ++i) {
        int j = base + i;
        if (j < NNODES) {
            offsets[j] = run;
            cursor[j] = run;
            run += counts[j];
        }
    }
    if (tid == 0) offsets[NNODES] = scan[256];
}

// ---------------- K4: fill perm with unmasked step ids grouped by node ------
__global__ __launch_bounds__(256) void k_perm(const int* __restrict__ mask,
                                              const int* __restrict__ nidx,
                                              int* __restrict__ cursor,
                                              int* __restrict__ perm) {
    const int step = blockIdx.x * 256 + threadIdx.x;
    if (step >= NSTEPS) return;
    if (!mask[step]) return;
    const int node = nidx[step];
    int p = atomicAdd(&cursor[node], 1);
    perm[p] = step;
}

// ---------------- K5: wave-per-node online-softmax weighted accumulate ------
// x read ONCE per unmasked step; no __syncthreads in hot loop.
__global__ __launch_bounds__(256) void k_combine(const float* __restrict__ x,
                                                 const float* __restrict__ q,
                                                 const int* __restrict__ offsets,
                                                 const int* __restrict__ perm,
                                                 float* __restrict__ update) {
    const int wave = threadIdx.x >> 6;
    const int lane = threadIdx.x & 63;
    const int node = blockIdx.x * 4 + wave;
    if (node >= NNODES) return;
    const int off = offsets[node];
    const int cnt = offsets[node + 1] - off;

    const float4* x4 = reinterpret_cast<const float4*>(x);
    float4 qa = reinterpret_cast<const float4*>(q)[(size_t)node * 64 + lane];

    float4 acc = make_float4(0.f, 0.f, 0.f, 0.f);
    float m = -3.0e38f;
    float l = 0.f;

    // prefetch depth 1
    int step = (cnt > 0) ? perm[off] : 0;
    float4 xa = (cnt > 0) ? x4[(size_t)step * 64 + lane]
                          : make_float4(0.f, 0.f, 0.f, 0.f);

    for (int i = 0; i < cnt; ++i) {
        // issue next-iteration loads before consuming current
        int step_n = 0;
        if (i + 1 < cnt) step_n = perm[off + i + 1];
        float4 xn = make_float4(0.f, 0.f, 0.f, 0.f);
        if (i + 1 < cnt) xn = x4[(size_t)step_n * 64 + lane];

        float s = xa.x * qa.x + xa.y * qa.y + xa.z * qa.z + xa.w * qa.w;
        s += __shfl_xor(s, 32);
        s += __shfl_xor(s, 16);
        s += __shfl_xor(s, 8);
        s += __shfl_xor(s, 4);
        s += __shfl_xor(s, 2);
        s += __shfl_xor(s, 1);
        s *= 0.0625f;  // 1/sqrt(256)

        float mn = fmaxf(m, s);
        float scale = __expf(m - mn);   // first iter: exp(-huge) = 0
        float w = __expf(s - mn);
        l = l * scale + w;
        acc.x = acc.x * scale + w * xa.x;
        acc.y = acc.y * scale + w * xa.y;
        acc.z = acc.z * scale + w * xa.z;
        acc.w = acc.w * scale + w * xa.w;
        m = mn;

        xa = xn;
    }

    const float inv = 1.f / fmaxf(l, 1e-9f);  // cnt==0: acc=0 -> output 0
    float4 o = make_float4(acc.x * inv, acc.y * inv, acc.z * inv, acc.w * inv);
    reinterpret_cast<float4*>(update)[(size_t)node * 64 + lane] = o;
}

// ---------------- K6: gated blend ----------------
__global__ __launch_bounds__(256) void k_gate(const float* __restrict__ prev,
                                              const float* __restrict__ update,
                                              const float* __restrict__ gW,
                                              const float* __restrict__ gb,
                                              float* __restrict__ out) {
    __shared__ float pa[16][D];
    __shared__ float ua[16][D];
    const int tid = threadIdx.x;
    const int row0 = blockIdx.x * 16;
    for (int i = tid; i < 16 * D; i += 256) {
        int r = i >> 8, c = i & 255;
        int row = row0 + r;
        pa[r][c] = (row < NNODES) ? prev[row * D + c] : 0.f;
        ua[r][c] = (row < NNODES) ? update[row * D + c] : 0.f;
    }
    __syncthreads();
    float acc[16];
#pragma unroll
    for (int r = 0; r < 16; ++r) acc[r] = 0.f;
    for (int k = 0; k < D; k += 4) {
        float w0 = gW[(k + 0) * D + tid];
        float w1 = gW[(k + 1) * D + tid];
        float w2 = gW[(k + 2) * D + tid];
        float w3 = gW[(k + 3) * D + tid];
#pragma unroll
        for (int r = 0; r < 16; ++r) {
            float4 av = *reinterpret_cast<const float4*>(&pa[r][k]);
            acc[r] += av.x * w0 + av.y * w1 + av.z * w2 + av.w * w3;
        }
    }
    for (int k = 0; k < D; k += 4) {
        float w0 = gW[(256 + k + 0) * D + tid];
        float w1 = gW[(256 + k + 1) * D + tid];
        float w2 = gW[(256 + k + 2) * D + tid];
        float w3 = gW[(256 + k + 3) * D + tid];
#pragma unroll
        for (int r = 0; r < 16; ++r) {
            float4 av = *reinterpret_cast<const float4*>(&ua[r][k]);
            acc[r] += av.x * w0 + av.y * w1 + av.z * w2 + av.w * w3;
        }
    }
    const float b = gb[tid];
    for (int r = 0; r < 16; ++r) {
        int row = row0 + r;
        if (row < NNODES) {
            float g = 1.f / (1.f + expf(-(acc[r] + b)));
            out[row * D + tid] = g * pa[r][tid] + (1.f - g) * ua[r][tid];
        }
    }
}

extern "C" void kernel_launch(void* const* d_in, const int* in_sizes, int n_in,
                              void* d_out, int out_size, void* d_ws, size_t ws_size,
                              hipStream_t stream) {
    const float* enc   = (const float*)d_in[0];  // [4096,64,256]
    const int*   mask  = (const int*)d_in[1];    // [4096,64]
    const int*   nidx  = (const int*)d_in[2];    // [4096,64]
    const float* prev  = (const float*)d_in[3];  // [10000,256]
    const float* Wq    = (const float*)d_in[4];  // [256,256]
    const float* gW    = (const float*)d_in[5];  // [512,256]
    const float* gb    = (const float*)d_in[6];  // [256]
    float* out = (float*)d_out;

    // workspace layout (256B-aligned)
    char* ws = (char*)d_ws;
    float* q       = (float*)(ws + 0);           // 10,240,000 B
    int*   counts  = (int*)  (ws + 10240000);    //     40,000 B
    int*   offsets = (int*)  (ws + 10280192);    //     40,004 B
    int*   cursor  = (int*)  (ws + 10320640);    //     40,000 B
    int*   perm    = (int*)  (ws + 10360832);    //  1,048,576 B
    float* update  = (float*)(ws + 11409408);    // 10,240,000 B

    hipMemsetAsync(counts, 0, NNODES * sizeof(int), stream);

    k_query<<<(NNODES + 31) / 32, 256, 0, stream>>>(prev, Wq, q);
    k_count<<<NSTEPS / 256, 256, 0, stream>>>(mask, nidx, counts);
    k_scan<<<1, 256, 0, stream>>>(counts, offsets, cursor);
    k_perm<<<NSTEPS / 256, 256, 0, stream>>>(mask, nidx, cursor, perm);
    k_combine<<<(NNODES + 3) / 4, 256, 0, stream>>>(enc, q, offsets, perm, update);
    k_gate<<<(NNODES + 15) / 16, 256, 0, stream>>>(prev, update, gW, gb, out);
}

// Round 3
// 535.522 us; speedup vs baseline: 1.1368x; 1.0922x over previous
//
#include <hip/hip_runtime.h>

#define D 256
#define NPATHS 4096
#define PLEN 64
#define NSTEPS (NPATHS * PLEN)   /* 262144 */
#define NNODES 10000

__device__ __forceinline__ void fma4(float4& acc, float s, const float4& w) {
    acc.x += s * w.x; acc.y += s * w.y; acc.z += s * w.z; acc.w += s * w.w;
}

// ---------------- K1: q = prev @ Wq  [NNODES, D] ----------------
// one wave per block, 8 rows/wave; A via wave-uniform scalar loads (s_load),
// W streamed coalesced (float4/lane = 4 owned columns). No LDS.
#define QR 8
__global__ __launch_bounds__(64) void k_query(const float* __restrict__ prev,
                                              const float* __restrict__ Wq,
                                              float* __restrict__ q) {
    const int lane = threadIdx.x;
    const int row0 = blockIdx.x * QR;          // 1250 blocks, exact
    const float4* W4 = reinterpret_cast<const float4*>(Wq);   // [256][64]
    float4 acc[QR];
#pragma unroll
    for (int r = 0; r < QR; ++r) acc[r] = make_float4(0.f, 0.f, 0.f, 0.f);

    for (int k4 = 0; k4 < 64; ++k4) {
        float4 w0 = W4[(k4 * 4 + 0) * 64 + lane];
        float4 w1 = W4[(k4 * 4 + 1) * 64 + lane];
        float4 w2 = W4[(k4 * 4 + 2) * 64 + lane];
        float4 w3 = W4[(k4 * 4 + 3) * 64 + lane];
#pragma unroll
        for (int r = 0; r < QR; ++r) {
            float4 a = *reinterpret_cast<const float4*>(&prev[(size_t)(row0 + r) * D + k4 * 4]);
            fma4(acc[r], a.x, w0);
            fma4(acc[r], a.y, w1);
            fma4(acc[r], a.z, w2);
            fma4(acc[r], a.w, w3);
        }
    }
    float4* Q4 = reinterpret_cast<float4*>(q);
#pragma unroll
    for (int r = 0; r < QR; ++r) Q4[(size_t)(row0 + r) * 64 + lane] = acc[r];
}

// ---------------- K2: per-node histogram of unmasked steps ----------------
__global__ __launch_bounds__(256) void k_count(const int* __restrict__ mask,
                                               const int* __restrict__ nidx,
                                               int* __restrict__ counts) {
    const int step = blockIdx.x * 256 + threadIdx.x;
    if (step >= NSTEPS) return;
    if (!mask[step]) return;
    atomicAdd(&counts[nidx[step]], 1);
}

// ---------------- K3: exclusive scan of counts -> offsets (+cursor copy) ----
// shfl wave-scan; no serial thread-0 chain.
__global__ __launch_bounds__(256) void k_scan(const int* __restrict__ counts,
                                              int* __restrict__ offsets,
                                              int* __restrict__ cursor) {
    const int tid = threadIdx.x;
    const int lane = tid & 63;
    const int w = tid >> 6;
    const int CH = 40;  // 256*40 = 10240 >= NNODES
    const int base = tid * CH;
    int s = 0;
    for (int i = 0; i < CH; ++i) {
        int j = base + i;
        if (j < NNODES) s += counts[j];
    }
    // inclusive scan within wave
    int v = s;
    for (int d = 1; d < 64; d <<= 1) {
        int t = __shfl_up(v, d);
        if (lane >= d) v += t;
    }
    __shared__ int wsum[4];
    if (lane == 63) wsum[w] = v;
    __syncthreads();
    int woff = 0;
    for (int i = 0; i < w; ++i) woff += wsum[i];
    int run = woff + v - s;  // exclusive prefix of this thread's chunk
    for (int i = 0; i < CH; ++i) {
        int j = base + i;
        if (j < NNODES) {
            offsets[j] = run;
            cursor[j] = run;
            run += counts[j];
        }
    }
    if (tid == 255) offsets[NNODES] = run;  // chunks >= NNODES contribute 0
}

// ---------------- K4: fill perm with unmasked step ids grouped by node ------
__global__ __launch_bounds__(256) void k_perm(const int* __restrict__ mask,
                                              const int* __restrict__ nidx,
                                              int* __restrict__ cursor,
                                              int* __restrict__ perm) {
    const int step = blockIdx.x * 256 + threadIdx.x;
    if (step >= NSTEPS) return;
    if (!mask[step]) return;
    const int node = nidx[step];
    int p = atomicAdd(&cursor[node], 1);
    perm[p] = step;
}

// ---------------- K5: wave-per-node online-softmax weighted accumulate ------
// perm chunk loaded coalesced (64 entries), step-ids broadcast via shfl,
// x-row loads software-pipelined depth 2. x read ONCE per unmasked step.
__global__ __launch_bounds__(256) void k_combine(const float* __restrict__ x,
                                                 const float* __restrict__ q,
                                                 const int* __restrict__ offsets,
                                                 const int* __restrict__ perm,
                                                 float* __restrict__ update) {
    const int wave = threadIdx.x >> 6;
    const int lane = threadIdx.x & 63;
    const int node = blockIdx.x * 4 + wave;
    if (node >= NNODES) return;
    const int off = offsets[node];
    const int cnt = offsets[node + 1] - off;

    const float4* x4 = reinterpret_cast<const float4*>(x);
    float4 qa = reinterpret_cast<const float4*>(q)[(size_t)node * 64 + lane];

    float4 acc = make_float4(0.f, 0.f, 0.f, 0.f);
    float m = -3.0e38f;
    float l = 0.f;

    for (int base = 0; base < cnt; base += 64) {
        const int lim = min(64, cnt - base);
        // coalesced chunk read of step ids (garbage beyond lim is never used)
        int myperm = perm[off + base + lane];

        float4 xs0, xs1;
        {
            int s0 = __shfl(myperm, 0);
            xs0 = x4[(size_t)s0 * 64 + lane];
        }
        if (lim > 1) {
            int s1 = __shfl(myperm, 1);
            xs1 = x4[(size_t)s1 * 64 + lane];
        }
        for (int i = 0; i < lim; ++i) {
            float4 cur = (i & 1) ? xs1 : xs0;
            if (i + 2 < lim) {
                int sn = __shfl(myperm, i + 2);
                float4 xn = x4[(size_t)sn * 64 + lane];
                if (i & 1) xs1 = xn; else xs0 = xn;
            }
            float s = cur.x * qa.x + cur.y * qa.y + cur.z * qa.z + cur.w * qa.w;
            s += __shfl_xor(s, 32);
            s += __shfl_xor(s, 16);
            s += __shfl_xor(s, 8);
            s += __shfl_xor(s, 4);
            s += __shfl_xor(s, 2);
            s += __shfl_xor(s, 1);
            s *= 0.0625f;  // 1/sqrt(256)

            float mn = fmaxf(m, s);
            float scale = __expf(m - mn);  // first iter: exp(-huge)=0
            float wgt = __expf(s - mn);
            l = l * scale + wgt;
            acc.x = acc.x * scale + wgt * cur.x;
            acc.y = acc.y * scale + wgt * cur.y;
            acc.z = acc.z * scale + wgt * cur.z;
            acc.w = acc.w * scale + wgt * cur.w;
            m = mn;
        }
    }

    const float inv = 1.f / fmaxf(l, 1e-9f);  // cnt==0: acc=0 -> output 0
    float4 o = make_float4(acc.x * inv, acc.y * inv, acc.z * inv, acc.w * inv);
    reinterpret_cast<float4*>(update)[(size_t)node * 64 + lane] = o;
}

// ---------------- K6: gated blend ----------------
// same scalar-broadcast GEMV structure as k_query; K=512 in two halves.
#define GR 8
__global__ __launch_bounds__(64) void k_gate(const float* __restrict__ prev,
                                             const float* __restrict__ update,
                                             const float* __restrict__ gW,
                                             const float* __restrict__ gb,
                                             float* __restrict__ out) {
    const int lane = threadIdx.x;
    const int row0 = blockIdx.x * GR;          // 1250 blocks, exact
    const float4* W4 = reinterpret_cast<const float4*>(gW);   // [512][64]
    float4 acc[GR];
#pragma unroll
    for (int r = 0; r < GR; ++r) acc[r] = make_float4(0.f, 0.f, 0.f, 0.f);

    for (int k4 = 0; k4 < 64; ++k4) {
        float4 w0 = W4[(k4 * 4 + 0) * 64 + lane];
        float4 w1 = W4[(k4 * 4 + 1) * 64 + lane];
        float4 w2 = W4[(k4 * 4 + 2) * 64 + lane];
        float4 w3 = W4[(k4 * 4 + 3) * 64 + lane];
#pragma unroll
        for (int r = 0; r < GR; ++r) {
            float4 a = *reinterpret_cast<const float4*>(&prev[(size_t)(row0 + r) * D + k4 * 4]);
            fma4(acc[r], a.x, w0);
            fma4(acc[r], a.y, w1);
            fma4(acc[r], a.z, w2);
            fma4(acc[r], a.w, w3);
        }
    }
    for (int k4 = 0; k4 < 64; ++k4) {
        float4 w0 = W4[(256 + k4 * 4 + 0) * 64 + lane];
        float4 w1 = W4[(256 + k4 * 4 + 1) * 64 + lane];
        float4 w2 = W4[(256 + k4 * 4 + 2) * 64 + lane];
        float4 w3 = W4[(256 + k4 * 4 + 3) * 64 + lane];
#pragma unroll
        for (int r = 0; r < GR; ++r) {
            float4 a = *reinterpret_cast<const float4*>(&update[(size_t)(row0 + r) * D + k4 * 4]);
            fma4(acc[r], a.x, w0);
            fma4(acc[r], a.y, w1);
            fma4(acc[r], a.z, w2);
            fma4(acc[r], a.w, w3);
        }
    }
    const float4* P4 = reinterpret_cast<const float4*>(prev);
    const float4* U4 = reinterpret_cast<const float4*>(update);
    const float4 b4 = reinterpret_cast<const float4*>(gb)[lane];
    float4* O4 = reinterpret_cast<float4*>(out);
#pragma unroll
    for (int r = 0; r < GR; ++r) {
        const size_t ri = (size_t)(row0 + r) * 64 + lane;
        float4 p = P4[ri];
        float4 u = U4[ri];
        float gx = 1.f / (1.f + __expf(-(acc[r].x + b4.x)));
        float gy = 1.f / (1.f + __expf(-(acc[r].y + b4.y)));
        float gz = 1.f / (1.f + __expf(-(acc[r].z + b4.z)));
        float gw = 1.f / (1.f + __expf(-(acc[r].w + b4.w)));
        float4 o;
        o.x = gx * p.x + (1.f - gx) * u.x;
        o.y = gy * p.y + (1.f - gy) * u.y;
        o.z = gz * p.z + (1.f - gz) * u.z;
        o.w = gw * p.w + (1.f - gw) * u.w;
        O4[ri] = o;
    }
}

extern "C" void kernel_launch(void* const* d_in, const int* in_sizes, int n_in,
                              void* d_out, int out_size, void* d_ws, size_t ws_size,
                              hipStream_t stream) {
    const float* enc   = (const float*)d_in[0];  // [4096,64,256]
    const int*   mask  = (const int*)d_in[1];    // [4096,64]
    const int*   nidx  = (const int*)d_in[2];    // [4096,64]
    const float* prev  = (const float*)d_in[3];  // [10000,256]
    const float* Wq    = (const float*)d_in[4];  // [256,256]
    const float* gW    = (const float*)d_in[5];  // [512,256]
    const float* gb    = (const float*)d_in[6];  // [256]
    float* out = (float*)d_out;

    // workspace layout (256B-aligned)
    char* ws = (char*)d_ws;
    float* q       = (float*)(ws + 0);           // 10,240,000 B
    int*   counts  = (int*)  (ws + 10240000);    //     40,000 B
    int*   offsets = (int*)  (ws + 10280192);    //     40,004 B
    int*   cursor  = (int*)  (ws + 10320640);    //     40,000 B
    int*   perm    = (int*)  (ws + 10360832);    //  1,048,576 B
    float* update  = (float*)(ws + 11409408);    // 10,240,000 B

    hipMemsetAsync(counts, 0, NNODES * sizeof(int), stream);

    k_query<<<NNODES / QR, 64, 0, stream>>>(prev, Wq, q);
    k_count<<<NSTEPS / 256, 256, 0, stream>>>(mask, nidx, counts);
    k_scan<<<1, 256, 0, stream>>>(counts, offsets, cursor);
    k_perm<<<NSTEPS / 256, 256, 0, stream>>>(mask, nidx, cursor, perm);
    k_combine<<<(NNODES + 3) / 4, 256, 0, stream>>>(enc, q, offsets, perm, update);
    k_gate<<<NNODES / GR, 64, 0, stream>>>(prev, update, gW, gb, out);
}